// Round 8
// baseline (161.210 us; speedup 1.0000x reference)
//
#include <hip/hip_runtime.h>
#include <stdint.h>

#define B_DIM 32768
#define IN_DIM 512
#define OUT_DIM 512

typedef float f32x4 __attribute__((ext_vector_type(4)));

// xi = trunc(v*2^sf); keep top-4 significant bits of |xi|; sign restored.
// fp32-bit path: truncf, then mask mantissa to 3 stored bits (+implicit = 4
// significant). The masked value is an integer with <=4 significant bits and
// |v| <= ~370 < 448 = e4m3 max, so OCP e4m3 represents it EXACTLY ->
// cvt_pk_fp8_f32 is lossless here (verified absmax=0 in R4/R6).
__device__ __forceinline__ float trunc4(float x, float s) {
    uint32_t u = __float_as_uint(truncf(x * s));
    return __uint_as_float(u & 0xFFF00000u);   // sign+exp+3 mantissa bits
}

// Merged quant: one dispatch covers x (nx4 words) then w (nw4 words).
// Read-BW-bound (85 MB ~ 13.5 us at 6.3 TB/s) -> at its roofline.
__global__ void quant_fp8_2(const float* __restrict__ x, const float* __restrict__ w,
                            uint32_t* __restrict__ ox, uint32_t* __restrict__ ow,
                            int nx4, int nw4,
                            const int* __restrict__ asf, const int* __restrict__ wsf) {
    int i = blockIdx.x * blockDim.x + threadIdx.x;
    const float4* in;
    uint32_t* out;
    float scale;
    if (i < nx4) {
        in = (const float4*)x + i;  out = ox + i;  scale = (float)(1 << *asf);
    } else {
        int j = i - nx4;
        if (j >= nw4) return;
        in = (const float4*)w + j;  out = ow + j;  scale = (float)(1 << *wsf);
    }
    float4 v = *in;
    int p = 0;
    p = __builtin_amdgcn_cvt_pk_fp8_f32(trunc4(v.x, scale), trunc4(v.y, scale), p, false);
    p = __builtin_amdgcn_cvt_pk_fp8_f32(trunc4(v.z, scale), trunc4(v.w, scale), p, true);
    *out = (uint32_t)p;   // byte j = element j (k-ascending)
}

// fp8 GEMM, R6's verified 2-phase double-buffered single-barrier pipeline,
// widened to a 128(M) x 256(N) tile with 512 threads / 8 waves (2M x 4N).
// Per-wave work is byte-identical to R6 (64x64 output, acc[4][4], 32 MFMA +
// 16 ds_read_b64 per K-step). The win: the A-tile is staged ONCE for both
// 128-col halves -> per-CU staging drops 64->48 KB per K-step (-25%), glds
// instruction count -25%, while per-CU MFMA work is unchanged. m233: the
// 2-phase critical path is ~72% stage+wait+barrier -> cutting its bytes 25%
// attacks the dominant term without touching the verified sync structure.
//   iter k: issue glds STAGE(k+1) -> buf[nxt]  (1xA + 2xB per thread)
//           ds_read frags + 32 MFMA on buf[cur]
//           s_waitcnt vmcnt(0) lgkmcnt(0); s_barrier   (ONE per K-step)
// LDS swizzle unchanged: row m's 8B k-unit u at physical u ^ (m&6), applied
// on the glds global source (even mask keeps 16B chunks contiguous).
__global__ __launch_bounds__(512, 6)
void gemm_f8(const uint8_t* __restrict__ A, const uint8_t* __restrict__ W,
             const float* __restrict__ bias, float* __restrict__ C,
             const int* __restrict__ wsf, const int* __restrict__ asf) {
    __shared__ uint8_t As[2][128 * 64];
    __shared__ uint8_t Bs[2][256 * 64];

    const int t    = threadIdx.x;
    const int w    = t >> 6;
    const int lane = t & 63;

    // XCD swizzle (bijective over 512 blocks): each XCD gets 32 contiguous
    // M-bands x 2 N-blocks (A L2 reuse within the XCD).
    const int b    = blockIdx.x;
    const int xcd  = b & 7;
    const int bm   = xcd * 32 + (b >> 4);
    const int bn   = (b >> 3) & 1;
    const int row0 = bm * 128;
    const int col0 = bn * 256;
    const int wm   = (w & 1) * 64;
    const int wn   = (w >> 1) * 64;

    // staging: thread t covers physical 16B chunk t (A: rows 0..127, 1 chunk;
    // B: 2 passes i, rows i*128 + 0..127). row m = (pass)*128 + (t>>2);
    // chunk j = t&3 -> global byte offset in row = ((2j) ^ (m&6)) * 8.
    const int m_st = t >> 2;                       // 0..127 (i*128 === 0 mod 8)
    const int goff = ((2 * (t & 3)) ^ (m_st & 6)) * 8;
    const size_t offA = (size_t)(row0 + m_st) * IN_DIM + goff;
    const size_t offB = (size_t)(col0 + m_st) * IN_DIM + goff;

    f32x4 acc[4][4];
    #pragma unroll
    for (int mt = 0; mt < 4; ++mt)
        #pragma unroll
        for (int nt = 0; nt < 4; ++nt)
            acc[mt][nt] = 0.0f;

    // ---- prologue: stage tile 0 into buffer 0 (one exposed latency) ----
    {
        const uint8_t* ga = A + offA;
        uint8_t*       la = &As[0][w * 1024];          // + lane*16B by HW
        __builtin_amdgcn_global_load_lds((const __attribute__((address_space(1))) void*)ga,
                                         (__attribute__((address_space(3))) void*)la, 16, 0, 0);
        #pragma unroll
        for (int i = 0; i < 2; ++i) {
            const uint8_t* gb = W + offB + (size_t)i * 128 * IN_DIM;
            uint8_t*       lb = &Bs[0][i * 8192 + w * 1024];
            __builtin_amdgcn_global_load_lds((const __attribute__((address_space(1))) void*)gb,
                                             (__attribute__((address_space(3))) void*)lb, 16, 0, 0);
        }
    }
    asm volatile("s_waitcnt vmcnt(0) lgkmcnt(0)" ::: "memory");
    __builtin_amdgcn_sched_barrier(0);
    __builtin_amdgcn_s_barrier();
    __builtin_amdgcn_sched_barrier(0);

    #pragma unroll
    for (int k = 0; k < 8; ++k) {
        const int cur = k & 1;
        const int nxt = cur ^ 1;

        // ---- issue STAGE(k+1) early: in flight across the MFMA phase ----
        if (k < 7) {
            const uint8_t* ga = A + offA + (k + 1) * 64;
            uint8_t*       la = &As[nxt][w * 1024];
            __builtin_amdgcn_global_load_lds((const __attribute__((address_space(1))) void*)ga,
                                             (__attribute__((address_space(3))) void*)la, 16, 0, 0);
            #pragma unroll
            for (int i = 0; i < 2; ++i) {
                const uint8_t* gb = W + offB + (size_t)i * 128 * IN_DIM + (k + 1) * 64;
                uint8_t*       lb = &Bs[nxt][i * 8192 + w * 1024];
                __builtin_amdgcn_global_load_lds((const __attribute__((address_space(1))) void*)gb,
                                                 (__attribute__((address_space(3))) void*)lb, 16, 0, 0);
            }
        }
        __builtin_amdgcn_sched_barrier(0);   // pin: glds issued before compute

        // ---- MFMA phase on buffers[cur] (identical to verified R6) ----
        {
            const int q  = lane >> 4;
            const int rl = lane & 15;
            const int sx = rl & 6;              // = row&6 (wm/wn, *16 mult of 8)
            #pragma unroll
            for (int ks = 0; ks < 2; ++ks) {
                const int c  = ks * 4 + q;      // logical 8B k-unit
                const int cb = (c ^ sx) * 8;    // swizzled byte offset in row
                long af[4], bfr[4];
                #pragma unroll
                for (int mt = 0; mt < 4; ++mt)
                    af[mt] = *(const long*)(&As[cur][0] + (wm + mt * 16 + rl) * 64 + cb);
                #pragma unroll
                for (int nt = 0; nt < 4; ++nt)
                    bfr[nt] = *(const long*)(&Bs[cur][0] + (wn + nt * 16 + rl) * 64 + cb);
                #pragma unroll
                for (int mt = 0; mt < 4; ++mt)
                    #pragma unroll
                    for (int nt = 0; nt < 4; ++nt)
                        acc[mt][nt] = __builtin_amdgcn_mfma_f32_16x16x32_fp8_fp8(af[mt], bfr[nt], acc[mt][nt], 0, 0, 0);
            }
        }

        // ---- ONE drain + barrier per K-step ----
        if (k < 7) {
            asm volatile("s_waitcnt vmcnt(0) lgkmcnt(0)" ::: "memory");
            __builtin_amdgcn_sched_barrier(0);
            __builtin_amdgcn_s_barrier();
            __builtin_amdgcn_sched_barrier(0);
        }
    }

    // epilogue: C/D layout col=lane&15, row=(lane>>4)*4+reg (dtype-independent)
    const float oscale = ldexpf(1.0f, -(*wsf + *asf));
    const int cl = lane & 15;
    const int rg = (lane >> 4) * 4;
    #pragma unroll
    for (int nt = 0; nt < 4; ++nt) {
        const int col = col0 + wn + nt * 16 + cl;
        const float bv = bias[col];
        #pragma unroll
        for (int mt = 0; mt < 4; ++mt) {
            f32x4 a = acc[mt][nt];
            #pragma unroll
            for (int r = 0; r < 4; ++r) {
                const int row = row0 + wm + mt * 16 + rg + r;
                C[(size_t)row * OUT_DIM + col] = a[r] * oscale + bv;
            }
        }
    }
}

extern "C" void kernel_launch(void* const* d_in, const int* in_sizes, int n_in,
                              void* d_out, int out_size, void* d_ws, size_t ws_size,
                              hipStream_t stream) {
    const float* x    = (const float*)d_in[0];
    const float* wgt  = (const float*)d_in[1];
    const float* bias = (const float*)d_in[2];
    const int*   wsf  = (const int*)d_in[3];
    const int*   asf  = (const int*)d_in[4];

    uint8_t* tx = (uint8_t*)d_ws;
    uint8_t* tw = (uint8_t*)d_ws + (size_t)B_DIM * IN_DIM;

    const int nx4 = B_DIM * IN_DIM / 4;
    const int nw4 = OUT_DIM * IN_DIM / 4;
    quant_fp8_2<<<(nx4 + nw4 + 255) / 256, 256, 0, stream>>>(
        x, wgt, (uint32_t*)tx, (uint32_t*)tw, nx4, nw4, asf, wsf);

    const int grid = (B_DIM / 128) * (OUT_DIM / 256); // 512
    gemm_f8<<<grid, 512, 0, stream>>>(tx, tw, bias, (float*)d_out, wsf, asf);
}

// Round 9
// 134.916 us; speedup vs baseline: 1.1949x; 1.1949x over previous
//
#include <hip/hip_runtime.h>
#include <stdint.h>

#define B_DIM 32768
#define IN_DIM 512
#define OUT_DIM 512

typedef float f32x4 __attribute__((ext_vector_type(4)));
typedef long long2_t __attribute__((ext_vector_type(2)));

// xi = trunc(v*2^sf); keep top-4 significant bits of |xi|; sign restored.
// fp32-bit path: truncf, then mask mantissa to 3 stored bits (+implicit = 4
// significant). The masked value is an integer with <=4 significant bits and
// |v| <= ~370 < 448 = e4m3 max, so OCP e4m3 represents it EXACTLY ->
// cvt_pk_fp8_f32 is lossless here (verified absmax=0 in R4/R6).
__device__ __forceinline__ float trunc4(float x, float s) {
    uint32_t u = __float_as_uint(truncf(x * s));
    return __uint_as_float(u & 0xFFF00000u);   // sign+exp+3 mantissa bits
}

// Merged quant: one dispatch covers x (nx4 words) then w (nw4 words).
// Read-BW-bound (85 MB ~ 13.5 us at 6.3 TB/s) -> at its roofline.
__global__ void quant_fp8_2(const float* __restrict__ x, const float* __restrict__ w,
                            uint32_t* __restrict__ ox, uint32_t* __restrict__ ow,
                            int nx4, int nw4,
                            const int* __restrict__ asf, const int* __restrict__ wsf) {
    int i = blockIdx.x * blockDim.x + threadIdx.x;
    const float4* in;
    uint32_t* out;
    float scale;
    if (i < nx4) {
        in = (const float4*)x + i;  out = ox + i;  scale = (float)(1 << *asf);
    } else {
        int j = i - nx4;
        if (j >= nw4) return;
        in = (const float4*)w + j;  out = ow + j;  scale = (float)(1 << *wsf);
    }
    float4 v = *in;
    int p = 0;
    p = __builtin_amdgcn_cvt_pk_fp8_f32(trunc4(v.x, scale), trunc4(v.y, scale), p, false);
    p = __builtin_amdgcn_cvt_pk_fp8_f32(trunc4(v.z, scale), trunc4(v.w, scale), p, true);
    *out = (uint32_t)p;   // byte j = element j (k-ascending)
}

// fp8 GEMM = verified R6 2-phase double-buffered single-barrier pipeline,
// with ONE change: b128-pair fragment reads (R8 counters exposed the old
// ds_read_b64 path as a 4-cycle/instr bank conflict: 2.1M = 4 x 524288 ops).
// K-permutation trick: MFMA k-order is arbitrary if A and B use the SAME
// order (dot product is order-invariant; exact here since all products and
// partial sums are integers < 2^24 -> fp32 addition is associative on them).
// In the physical layout (unit p = u ^ (row&6), even mask) logical units
// (2q, 2q+1) are ADJACENT: one ds_read_b128 at chunk (q ^ ((rl>>1)&3))*16
// yields lo 8B = unit 2q -> even-units MFMA, hi 8B = unit 2q+1 -> odd-units
// MFMA. 8 b128 reads/K-step/wave instead of 16 b64; the b128 chunk profile
// (8 lanes per bank-quad) is the R1-R3 pattern that measured ZERO conflicts.
// Staging, glds addressing, sync structure, epilogue: byte-identical to R6.
__global__ __launch_bounds__(256, 4)
void gemm_f8(const uint8_t* __restrict__ A, const uint8_t* __restrict__ W,
             const float* __restrict__ bias, float* __restrict__ C,
             const int* __restrict__ wsf, const int* __restrict__ asf) {
    __shared__ uint8_t As[2][128 * 64];
    __shared__ uint8_t Bs[2][128 * 64];

    const int t    = threadIdx.x;
    const int w    = t >> 6;
    const int lane = t & 63;

    // XCD swizzle: 4 N-blocks of one M-band adjacent on one XCD (A L2 reuse).
    const int b    = blockIdx.x;
    const int xcd  = b & 7;
    const int slot = b >> 3;
    const int bm   = xcd * 32 + (slot >> 2);
    const int bn   = slot & 3;
    const int row0 = bm * 128;
    const int col0 = bn * 128;
    const int wm   = (w & 1) * 64;
    const int wn   = (w >> 1) * 64;

    // staging: pass i covers physical bytes [i*4096 + t*16, +16).
    // row m = i*64 + (t>>2); physical 16B unit j = t&3; global byte offset in
    // row = ((2j) ^ (m&6)) * 8  (16 contiguous bytes = 2 adjacent logical units).
    const int m_st = t >> 2;                       // 0..63 (+i*64; i*64 === 0 mod 8)
    const int goff = ((2 * (t & 3)) ^ (m_st & 6)) * 8;
    const size_t offA = (size_t)(row0 + m_st) * IN_DIM + goff;
    const size_t offB = (size_t)(col0 + m_st) * IN_DIM + goff;

    f32x4 acc[4][4];
    #pragma unroll
    for (int mt = 0; mt < 4; ++mt)
        #pragma unroll
        for (int nt = 0; nt < 4; ++nt)
            acc[mt][nt] = 0.0f;

    // ---- prologue: stage tile 0 into buffer 0 (one exposed latency) ----
    #pragma unroll
    for (int i = 0; i < 2; ++i) {
        const uint8_t* ga = A + offA + (size_t)i * 64 * IN_DIM;
        uint8_t*       la = &As[0][i * 4096 + w * 1024];   // + lane*16B by HW
        __builtin_amdgcn_global_load_lds((const __attribute__((address_space(1))) void*)ga,
                                         (__attribute__((address_space(3))) void*)la, 16, 0, 0);
        const uint8_t* gb = W + offB + (size_t)i * 64 * IN_DIM;
        uint8_t*       lb = &Bs[0][i * 4096 + w * 1024];
        __builtin_amdgcn_global_load_lds((const __attribute__((address_space(1))) void*)gb,
                                         (__attribute__((address_space(3))) void*)lb, 16, 0, 0);
    }
    asm volatile("s_waitcnt vmcnt(0) lgkmcnt(0)" ::: "memory");
    __builtin_amdgcn_sched_barrier(0);
    __builtin_amdgcn_s_barrier();
    __builtin_amdgcn_sched_barrier(0);

    #pragma unroll
    for (int k = 0; k < 8; ++k) {
        const int cur = k & 1;
        const int nxt = cur ^ 1;

        // ---- issue STAGE(k+1) early: in flight across the MFMA phase ----
        if (k < 7) {
            #pragma unroll
            for (int i = 0; i < 2; ++i) {
                const uint8_t* ga = A + offA + (size_t)i * 64 * IN_DIM + (k + 1) * 64;
                uint8_t*       la = &As[nxt][i * 4096 + w * 1024];
                __builtin_amdgcn_global_load_lds((const __attribute__((address_space(1))) void*)ga,
                                                 (__attribute__((address_space(3))) void*)la, 16, 0, 0);
                const uint8_t* gb = W + offB + (size_t)i * 64 * IN_DIM + (k + 1) * 64;
                uint8_t*       lb = &Bs[nxt][i * 4096 + w * 1024];
                __builtin_amdgcn_global_load_lds((const __attribute__((address_space(1))) void*)gb,
                                                 (__attribute__((address_space(3))) void*)lb, 16, 0, 0);
            }
        }
        __builtin_amdgcn_sched_barrier(0);   // pin: glds issued before compute

        // ---- MFMA phase on buffers[cur]: b128-pair reads, even/odd MFMAs ----
        {
            const int q  = lane >> 4;
            const int rl = lane & 15;
            const int ch = (q ^ ((rl >> 1) & 3)) * 16;  // b128 chunk byte offset
            long2_t af[4], bfr[4];
            #pragma unroll
            for (int mt = 0; mt < 4; ++mt)
                af[mt] = *(const long2_t*)(&As[cur][0] + (wm + mt * 16 + rl) * 64 + ch);
            #pragma unroll
            for (int nt = 0; nt < 4; ++nt)
                bfr[nt] = *(const long2_t*)(&Bs[cur][0] + (wn + nt * 16 + rl) * 64 + ch);
            #pragma unroll
            for (int mt = 0; mt < 4; ++mt)
                #pragma unroll
                for (int nt = 0; nt < 4; ++nt) {
                    acc[mt][nt] = __builtin_amdgcn_mfma_f32_16x16x32_fp8_fp8(af[mt].x, bfr[nt].x, acc[mt][nt], 0, 0, 0);
                    acc[mt][nt] = __builtin_amdgcn_mfma_f32_16x16x32_fp8_fp8(af[mt].y, bfr[nt].y, acc[mt][nt], 0, 0, 0);
                }
        }

        // ---- ONE drain + barrier per K-step ----
        if (k < 7) {
            asm volatile("s_waitcnt vmcnt(0) lgkmcnt(0)" ::: "memory");
            __builtin_amdgcn_sched_barrier(0);
            __builtin_amdgcn_s_barrier();
            __builtin_amdgcn_sched_barrier(0);
        }
    }

    // epilogue: C/D layout col=lane&15, row=(lane>>4)*4+reg (dtype-independent)
    const float oscale = ldexpf(1.0f, -(*wsf + *asf));
    const int cl = lane & 15;
    const int rg = (lane >> 4) * 4;
    #pragma unroll
    for (int nt = 0; nt < 4; ++nt) {
        const int col = col0 + wn + nt * 16 + cl;
        const float bv = bias[col];
        #pragma unroll
        for (int mt = 0; mt < 4; ++mt) {
            f32x4 a = acc[mt][nt];
            #pragma unroll
            for (int r = 0; r < 4; ++r) {
                const int row = row0 + wm + mt * 16 + rg + r;
                C[(size_t)row * OUT_DIM + col] = a[r] * oscale + bv;
            }
        }
    }
}

extern "C" void kernel_launch(void* const* d_in, const int* in_sizes, int n_in,
                              void* d_out, int out_size, void* d_ws, size_t ws_size,
                              hipStream_t stream) {
    const float* x    = (const float*)d_in[0];
    const float* wgt  = (const float*)d_in[1];
    const float* bias = (const float*)d_in[2];
    const int*   wsf  = (const int*)d_in[3];
    const int*   asf  = (const int*)d_in[4];

    uint8_t* tx = (uint8_t*)d_ws;
    uint8_t* tw = (uint8_t*)d_ws + (size_t)B_DIM * IN_DIM;

    const int nx4 = B_DIM * IN_DIM / 4;
    const int nw4 = OUT_DIM * IN_DIM / 4;
    quant_fp8_2<<<(nx4 + nw4 + 255) / 256, 256, 0, stream>>>(
        x, wgt, (uint32_t*)tx, (uint32_t*)tw, nx4, nw4, asf, wsf);

    const int grid = (B_DIM / 128) * (OUT_DIM / 128); // 1024
    gemm_f8<<<grid, 256, 0, stream>>>(tx, tw, bias, (float*)d_out, wsf, asf);
}

// Round 10
// 134.775 us; speedup vs baseline: 1.1961x; 1.0010x over previous
//
#include <hip/hip_runtime.h>
#include <stdint.h>

#define B_DIM 32768
#define IN_DIM 512
#define OUT_DIM 512

typedef float f32x4 __attribute__((ext_vector_type(4)));
typedef long long2_t __attribute__((ext_vector_type(2)));

// xi = trunc(v*2^sf); keep top-4 significant bits of |xi|; sign restored.
// fp32-bit path: truncf, then mask mantissa to 3 stored bits (+implicit = 4
// significant). The masked value is an integer with <=4 significant bits and
// |v| <= ~370 < 448 = e4m3 max, so OCP e4m3 represents it EXACTLY ->
// cvt_pk_fp8_f32 is lossless here (verified absmax=0 in R4/R6/R9).
__device__ __forceinline__ float trunc4(float x, float s) {
    uint32_t u = __float_as_uint(truncf(x * s));
    return __uint_as_float(u & 0xFFF00000u);   // sign+exp+3 mantissa bits
}

// Merged quant: one dispatch covers x (nx4 words) then w (nw4 words).
// Read-BW-bound (85 MB ~ 13.5 us at 6.3 TB/s) -> at its roofline.
__global__ void quant_fp8_2(const float* __restrict__ x, const float* __restrict__ w,
                            uint32_t* __restrict__ ox, uint32_t* __restrict__ ow,
                            int nx4, int nw4,
                            const int* __restrict__ asf, const int* __restrict__ wsf) {
    int i = blockIdx.x * blockDim.x + threadIdx.x;
    const float4* in;
    uint32_t* out;
    float scale;
    if (i < nx4) {
        in = (const float4*)x + i;  out = ox + i;  scale = (float)(1 << *asf);
    } else {
        int j = i - nx4;
        if (j >= nw4) return;
        in = (const float4*)w + j;  out = ow + j;  scale = (float)(1 << *wsf);
    }
    float4 v = *in;
    int p = 0;
    p = __builtin_amdgcn_cvt_pk_fp8_f32(trunc4(v.x, scale), trunc4(v.y, scale), p, false);
    p = __builtin_amdgcn_cvt_pk_fp8_f32(trunc4(v.z, scale), trunc4(v.w, scale), p, true);
    *out = (uint32_t)p;   // byte j = element j (k-ascending)
}

// fp8 GEMM: R8's 128(M) x 256(N) / 512-thread / 8-wave structure with R8's
// two measured defects removed:
//  1. __launch_bounds__(512,4) (NOT 6): VGPR cap 128 >= ~100 needed -> no
//     spill (R8: cap 85 -> VGPR_Count=40 + 56 MB scratch traffic).
//  2. R9's conflict-free b128-pair fragment reads (R8's b64 path: 2.1M
//     bank-conflict cycles = 4/instr).
// Mechanism kept from R8: A-tile staged ONCE for both 128-col halves ->
// per-CU staging bytes/K-step -25% on the stage-dominated 2-phase critical
// path (m233: ~72%). Grid 512 = exactly 2 blocks/CU -> zero tail.
// Sync structure = verified R6 2-phase single-barrier, byte-identical:
//   iter k: issue glds STAGE(k+1) -> buf[nxt]  (1xA + 2xB per thread)
//           b128-pair ds_read + 32 MFMA on buf[cur]
//           s_waitcnt vmcnt(0) lgkmcnt(0); s_barrier   (ONE per K-step)
// K-permutation trick (exact: integer products < 2^24, fp32 add associative
// on them): logical units (2q,2q+1) are adjacent in the physical layout
// (unit p = u ^ (row&6), even mask); one ds_read_b128 at chunk
// (q ^ ((rl>>1)&3))*16 feeds lo->even-unit MFMA, hi->odd-unit MFMA.
__global__ __launch_bounds__(512, 4)
void gemm_f8(const uint8_t* __restrict__ A, const uint8_t* __restrict__ W,
             const float* __restrict__ bias, float* __restrict__ C,
             const int* __restrict__ wsf, const int* __restrict__ asf) {
    __shared__ uint8_t As[2][128 * 64];
    __shared__ uint8_t Bs[2][256 * 64];

    const int t    = threadIdx.x;
    const int w    = t >> 6;
    const int lane = t & 63;

    // XCD swizzle (bijective over 512 blocks): b = (mslot<<4)|(bn<<3)|xcd.
    // Each XCD gets 32 contiguous M-bands x 2 N-blocks (A L2 reuse).
    const int b    = blockIdx.x;
    const int xcd  = b & 7;
    const int bm   = xcd * 32 + (b >> 4);
    const int bn   = (b >> 3) & 1;
    const int row0 = bm * 128;
    const int col0 = bn * 256;
    const int wm   = (w & 1) * 64;
    const int wn   = (w >> 1) * 64;

    // staging: thread t covers one 16B chunk per pass (A: rows 0..127 in one
    // pass; B: 2 passes of 128 rows). row m = pass*128 + (t>>2); chunk j=t&3;
    // global byte offset in row = ((2j) ^ (m&6)) * 8.
    const int m_st = t >> 2;                       // 0..127 (pass*128 === 0 mod 8)
    const int goff = ((2 * (t & 3)) ^ (m_st & 6)) * 8;
    const size_t offA = (size_t)(row0 + m_st) * IN_DIM + goff;
    const size_t offB = (size_t)(col0 + m_st) * IN_DIM + goff;

    f32x4 acc[4][4];
    #pragma unroll
    for (int mt = 0; mt < 4; ++mt)
        #pragma unroll
        for (int nt = 0; nt < 4; ++nt)
            acc[mt][nt] = 0.0f;

    // ---- prologue: stage tile 0 into buffer 0 (one exposed latency) ----
    {
        const uint8_t* ga = A + offA;
        uint8_t*       la = &As[0][w * 1024];          // + lane*16B by HW
        __builtin_amdgcn_global_load_lds((const __attribute__((address_space(1))) void*)ga,
                                         (__attribute__((address_space(3))) void*)la, 16, 0, 0);
        #pragma unroll
        for (int i = 0; i < 2; ++i) {
            const uint8_t* gb = W + offB + (size_t)i * 128 * IN_DIM;
            uint8_t*       lb = &Bs[0][i * 8192 + w * 1024];
            __builtin_amdgcn_global_load_lds((const __attribute__((address_space(1))) void*)gb,
                                             (__attribute__((address_space(3))) void*)lb, 16, 0, 0);
        }
    }
    asm volatile("s_waitcnt vmcnt(0) lgkmcnt(0)" ::: "memory");
    __builtin_amdgcn_sched_barrier(0);
    __builtin_amdgcn_s_barrier();
    __builtin_amdgcn_sched_barrier(0);

    #pragma unroll
    for (int k = 0; k < 8; ++k) {
        const int cur = k & 1;
        const int nxt = cur ^ 1;

        // ---- issue STAGE(k+1) early: in flight across the MFMA phase ----
        if (k < 7) {
            const uint8_t* ga = A + offA + (k + 1) * 64;
            uint8_t*       la = &As[nxt][w * 1024];
            __builtin_amdgcn_global_load_lds((const __attribute__((address_space(1))) void*)ga,
                                             (__attribute__((address_space(3))) void*)la, 16, 0, 0);
            #pragma unroll
            for (int i = 0; i < 2; ++i) {
                const uint8_t* gb = W + offB + (size_t)i * 128 * IN_DIM + (k + 1) * 64;
                uint8_t*       lb = &Bs[nxt][i * 8192 + w * 1024];
                __builtin_amdgcn_global_load_lds((const __attribute__((address_space(1))) void*)gb,
                                                 (__attribute__((address_space(3))) void*)lb, 16, 0, 0);
            }
        }
        __builtin_amdgcn_sched_barrier(0);   // pin: glds issued before compute

        // ---- MFMA phase on buffers[cur]: b128-pair reads, even/odd MFMAs ----
        {
            const int q  = lane >> 4;
            const int rl = lane & 15;
            const int ch = (q ^ ((rl >> 1) & 3)) * 16;  // b128 chunk byte offset
            long2_t af[4], bfr[4];
            #pragma unroll
            for (int mt = 0; mt < 4; ++mt)
                af[mt] = *(const long2_t*)(&As[cur][0] + (wm + mt * 16 + rl) * 64 + ch);
            #pragma unroll
            for (int nt = 0; nt < 4; ++nt)
                bfr[nt] = *(const long2_t*)(&Bs[cur][0] + (wn + nt * 16 + rl) * 64 + ch);
            #pragma unroll
            for (int mt = 0; mt < 4; ++mt)
                #pragma unroll
                for (int nt = 0; nt < 4; ++nt) {
                    acc[mt][nt] = __builtin_amdgcn_mfma_f32_16x16x32_fp8_fp8(af[mt].x, bfr[nt].x, acc[mt][nt], 0, 0, 0);
                    acc[mt][nt] = __builtin_amdgcn_mfma_f32_16x16x32_fp8_fp8(af[mt].y, bfr[nt].y, acc[mt][nt], 0, 0, 0);
                }
        }

        // ---- ONE drain + barrier per K-step ----
        if (k < 7) {
            asm volatile("s_waitcnt vmcnt(0) lgkmcnt(0)" ::: "memory");
            __builtin_amdgcn_sched_barrier(0);
            __builtin_amdgcn_s_barrier();
            __builtin_amdgcn_sched_barrier(0);
        }
    }

    // epilogue: C/D layout col=lane&15, row=(lane>>4)*4+reg (dtype-independent)
    const float oscale = ldexpf(1.0f, -(*wsf + *asf));
    const int cl = lane & 15;
    const int rg = (lane >> 4) * 4;
    #pragma unroll
    for (int nt = 0; nt < 4; ++nt) {
        const int col = col0 + wn + nt * 16 + cl;
        const float bv = bias[col];
        #pragma unroll
        for (int mt = 0; mt < 4; ++mt) {
            f32x4 a = acc[mt][nt];
            #pragma unroll
            for (int r = 0; r < 4; ++r) {
                const int row = row0 + wm + mt * 16 + rg + r;
                C[(size_t)row * OUT_DIM + col] = a[r] * oscale + bv;
            }
        }
    }
}

extern "C" void kernel_launch(void* const* d_in, const int* in_sizes, int n_in,
                              void* d_out, int out_size, void* d_ws, size_t ws_size,
                              hipStream_t stream) {
    const float* x    = (const float*)d_in[0];
    const float* wgt  = (const float*)d_in[1];
    const float* bias = (const float*)d_in[2];
    const int*   wsf  = (const int*)d_in[3];
    const int*   asf  = (const int*)d_in[4];

    uint8_t* tx = (uint8_t*)d_ws;
    uint8_t* tw = (uint8_t*)d_ws + (size_t)B_DIM * IN_DIM;

    const int nx4 = B_DIM * IN_DIM / 4;
    const int nw4 = OUT_DIM * IN_DIM / 4;
    quant_fp8_2<<<(nx4 + nw4 + 255) / 256, 256, 0, stream>>>(
        x, wgt, (uint32_t*)tx, (uint32_t*)tw, nx4, nw4, asf, wsf);

    const int grid = (B_DIM / 128) * (OUT_DIM / 256); // 512
    gemm_f8<<<grid, 512, 0, stream>>>(tx, tw, bias, (float*)d_out, wsf, asf);
}